// Round 1
// baseline (167.845 us; speedup 1.0000x reference)
//
#include <hip/hip_runtime.h>

// Harness promotes float16 tensors to float32: x, scales, out are f32;
// weight_packed is int32, one byte (2 nibbles) per element.
#define M 32
#define N 11008
#define K 4096
#define NGROUPS 32
#define BN 16                // n-rows per block
#define KSPLIT 4             // k-split across blocks
#define KRANGE (K / KSPLIT)  // 1024 k per block
#define KWAVE (KRANGE / 4)   // 256 k per wave (contiguous) = 2 scale groups
#define NSTEP (KWAVE / 32)   // 8 mfma k-steps per wave

typedef _Float16 half8 __attribute__((ext_vector_type(8))); // 4 VGPRs
typedef float floatx4 __attribute__((ext_vector_type(4)));
typedef float float8 __attribute__((ext_vector_type(8)));

// Barrier-free streaming design: every weight byte / x element feeds exactly
// ONE lane's MFMA fragment, so LDS staging has no reuse to exploit — load
// fragments straight from global into VGPRs. Per lane: 8 weight dwordx4
// issued upfront (128 B in flight, no vmcnt(0) drains, no barriers in the
// main loop). x is L2-resident (512 KB f32); converted f32->f16 in-register
// (exact: values are promoted f16), which removes the xcvt pre-pass and all
// d_ws usage.
__global__ __launch_bounds__(256) void int4_gemm_kernel(
    const float* __restrict__ x,      // [M][K] f32 (promoted f16)
    const int* __restrict__ wp,       // [N][K/2] int32, 2 nibbles each
    const float* __restrict__ scales, // [N][NGROUPS] f32
    float* __restrict__ out)          // [M][N] f32, pre-zeroed
{
    __shared__ float red[4 * 512];    // 8 KB, epilogue reduce only

    const int t    = threadIdx.x;
    const int lane = t & 63;
    const int w    = t >> 6;        // wave id: splits KRANGE 4-ways
    const int n0   = blockIdx.x * BN;
    const int ks   = blockIdx.y;    // k-split index
    const int row  = lane & 15;     // n-row of B / m-row of A fragments
    const int quad = lane >> 4;

    const int kbase = ks * KRANGE + w * KWAVE; // this wave's contiguous 256 k

    // weight fragment base: lane's n-row, k = kbase + quad*8 (+ 32 per step)
    // wave-wide: 16 rows x 64 B contiguous per load -> full-line coalescing
    const int*   gw = wp + (long)(n0 + row) * (K / 2) + (kbase >> 1) + quad * 4;
    const float* gx = x  + (long)row * K + kbase + quad * 8;

    // ---- issue all 8 weight loads upfront: the HBM stream, deep in flight ----
    int4 wv[NSTEP];
    #pragma unroll
    for (int s = 0; s < NSTEP; ++s)
        wv[s] = *(const int4*)(gw + s * 16); // +64 B per step (32 k)

    // wave's 256 k == exactly 2 scale groups of 128
    const float s0 = scales[(n0 + row) * NGROUPS + ks * 8 + w * 2 + 0];
    const float s1 = scales[(n0 + row) * NGROUPS + ks * 8 + w * 2 + 1];

    floatx4 acc0 = {0.f, 0.f, 0.f, 0.f};
    floatx4 acc1 = {0.f, 0.f, 0.f, 0.f};
    const half8 c1032 = (half8)(_Float16)1032.0f; // 0x6408, exact

    #pragma unroll
    for (int g = 0; g < 2; ++g) {
        floatx4 t0 = {0.f, 0.f, 0.f, 0.f};
        floatx4 t1 = {0.f, 0.f, 0.f, 0.f};
        #pragma unroll
        for (int si = 0; si < 4; ++si) {
            const int s = g * 4 + si;
            // A fragments from L2-resident x, cvt f32->f16 in-register (exact)
            float8 xa = *(const float8*)(gx + (long)s * 32);
            float8 xb = *(const float8*)(gx + 16 * K + (long)s * 32);
            half8 a0, a1;
            #pragma unroll
            for (int j = 0; j < 8; ++j) {
                a0[j] = (_Float16)xa[j];
                a1[j] = (_Float16)xb[j];
            }
            // B: 4 packed ints = 8 consecutive k of this lane's n-row
            uint4 uw;
            unsigned int b;
            b = (unsigned int)wv[s].x;
            uw.x = ((b | (b << 12)) & 0x000F000Fu) | 0x64006400u;
            b = (unsigned int)wv[s].y;
            uw.y = ((b | (b << 12)) & 0x000F000Fu) | 0x64006400u;
            b = (unsigned int)wv[s].z;
            uw.z = ((b | (b << 12)) & 0x000F000Fu) | 0x64006400u;
            b = (unsigned int)wv[s].w;
            uw.w = ((b | (b << 12)) & 0x000F000Fu) | 0x64006400u;
            half8 bf = __builtin_bit_cast(half8, uw) - c1032; // exact (nib-8)

            t0 = __builtin_amdgcn_mfma_f32_16x16x32_f16(a0, bf, t0, 0, 0, 0);
            t1 = __builtin_amdgcn_mfma_f32_16x16x32_f16(a1, bf, t1, 0, 0, 0);
        }
        const float sg = g ? s1 : s0;
        #pragma unroll
        for (int r = 0; r < 4; ++r) {
            acc0[r] += sg * t0[r]; // fp32 scale application, matches reference
            acc1[r] += sg * t1[r];
        }
    }

    // ---- epilogue: reduce 4 waves' k-partials in LDS, one atomic per out ----
    #pragma unroll
    for (int r = 0; r < 4; ++r) {
        // C/D layout: col(n) = lane&15, row(m) = quad*4 + r
        red[w * 512 + (quad * 4 + r) * 16 + row]      = acc0[r];
        red[w * 512 + (quad * 4 + r + 16) * 16 + row] = acc1[r];
    }
    __syncthreads();
    #pragma unroll
    for (int i = 0; i < 2; ++i) {
        const int o = t + 256 * i; // o = m*16 + n
        const float sum = red[o] + red[512 + o] + red[1024 + o] + red[1536 + o];
        const int m = o >> 4;
        const int n = o & 15;
        atomicAdd(&out[m * N + n0 + n], sum);
    }
}

extern "C" void kernel_launch(void* const* d_in, const int* in_sizes, int n_in,
                              void* d_out, int out_size, void* d_ws, size_t ws_size,
                              hipStream_t stream) {
    const float* x      = (const float*)d_in[0];
    const int* wp       = (const int*)d_in[1];
    const float* scales = (const float*)d_in[2];
    float* out          = (float*)d_out;

    hipMemsetAsync(out, 0, (size_t)M * N * sizeof(float), stream);
    int4_gemm_kernel<<<dim3(N / BN, KSPLIT), 256, 0, stream>>>(x, wp, scales, out);
}

// Round 3
// 151.344 us; speedup vs baseline: 1.1090x; 1.1090x over previous
//
#include <hip/hip_runtime.h>

// Harness promotes float16 tensors to float32: x, scales, out are f32;
// weight_packed is int32, ONE BYTE (2 nibbles = 2 k-values) per element.
#define M 32
#define N 11008
#define K 4096
#define NGROUPS 32
#define BN 32                // n-rows per block
#define KSPLIT 4             // k-split across blocks
#define KRANGE (K / KSPLIT)  // 1024 k per block
#define BK 256               // k per staged chunk
#define NCHUNK (KRANGE / BK) // 4
#define WPAIR 260            // ints per LDS 2-row pair: 2*128 + 4 pad (bank spread)
#define RSTRIDE 36           // reduce-tile row stride (pad: 2-way max = free)
#define RWAVE (32 * RSTRIDE) // 1152 floats per wave partial

typedef _Float16 half8 __attribute__((ext_vector_type(8))); // 4 VGPRs
typedef _Float16 half2v __attribute__((ext_vector_type(2)));
typedef float floatx4 __attribute__((ext_vector_type(4)));
typedef float float8 __attribute__((ext_vector_type(8)));

__device__ inline void gll16(const void* g, void* l) {
    __builtin_amdgcn_global_load_lds(
        (const __attribute__((address_space(1))) unsigned int*)g,
        (__attribute__((address_space(3))) unsigned int*)l, 16, 0, 0);
}

// f32 -> f16, exact for promoted-f16 inputs (rtz == rne when representable)
__device__ inline half8 cvt8(float8 v) {
    half8 r; half2v p;
    p = __builtin_bit_cast(half2v, __builtin_amdgcn_cvt_pkrtz(v[0], v[1])); r[0] = p[0]; r[1] = p[1];
    p = __builtin_bit_cast(half2v, __builtin_amdgcn_cvt_pkrtz(v[2], v[3])); r[2] = p[0]; r[3] = p[1];
    p = __builtin_bit_cast(half2v, __builtin_amdgcn_cvt_pkrtz(v[4], v[5])); r[4] = p[0]; r[5] = p[1];
    p = __builtin_bit_cast(half2v, __builtin_amdgcn_cvt_pkrtz(v[6], v[7])); r[6] = p[0]; r[7] = p[1];
    return r;
}

// 4 packed bytes -> 8 f16 values of (nibble - 8), exact via 0x6400 bias trick
__device__ inline half8 unpack8(int4 wv) {
    uint4 uw; unsigned int b;
    b = (unsigned)wv.x; uw.x = ((b | (b << 12)) & 0x000F000Fu) | 0x64006400u;
    b = (unsigned)wv.y; uw.y = ((b | (b << 12)) & 0x000F000Fu) | 0x64006400u;
    b = (unsigned)wv.z; uw.z = ((b | (b << 12)) & 0x000F000Fu) | 0x64006400u;
    b = (unsigned)wv.w; uw.w = ((b | (b << 12)) & 0x000F000Fu) | 0x64006400u;
    const half8 c1032 = (half8)(_Float16)1032.0f; // 0x6408, exact
    return __builtin_bit_cast(half8, uw) - c1032; // exact (nib - 8)
}

// Design: weights (the 90 MB HBM stream) staged via global_load_lds — zero
// VGPR cost, deep MLP, compiler can't serialize it. x (512 KB, L2-resident,
// zero intra-block reuse) goes straight to VGPRs, issued BEFORE the chunk
// barrier so its L2 latency hides under the barrier's vmcnt drain. BN=32
// halves x L2 traffic (344->172 MB) vs BN=16.
__global__ __launch_bounds__(256) void int4_gemm_kernel(
    const float* __restrict__ x,      // [M][K] f32 (promoted f16)
    const int* __restrict__ wp,       // [N][K/2] int32, 2 nibbles each
    const float* __restrict__ scales, // [N][NGROUPS] f32
    float* __restrict__ out)          // [M][N] f32, pre-zeroed
{
    __shared__ int lds[4 * RWAVE];    // 18.4 KB: w-tiles (16.3 KB) / reduce alias
    int*   wsh = lds;
    float* red = (float*)lds;

    const int t    = threadIdx.x;
    const int lane = t & 63;
    const int w    = t >> 6;        // wave id: splits chunk k 4-ways
    const int n0   = blockIdx.x * BN;
    const int ks   = blockIdx.y;    // k-split index
    const int row  = lane & 15;     // n/m-row within fragments
    const int quad = lane >> 4;

    floatx4 acc00 = {0,0,0,0}, acc01 = {0,0,0,0};
    floatx4 acc10 = {0,0,0,0}, acc11 = {0,0,0,0};

    const float* gx0 = x + (long)row * K + ks * KRANGE + quad * 8;
    const float* gx1 = gx0 + 16 * K;
    const int woff = w * 64;        // wave's k-base inside chunk

    for (int c = 0; c < NCHUNK; ++c) {
        const int kc = ks * KRANGE + c * BK; // global chunk k-base

        // ---- stage weights: 16 pairs x 1KB, 4 per wave, lane-contiguous ----
        #pragma unroll
        for (int i = 0; i < 4; ++i) {
            int p = w * 4 + i;               // pair 0..15
            int r = 2 * p + (lane >> 5);     // row this lane serves
            const int* gsrc = wp + (long)(n0 + r) * (K / 2) + (kc >> 1) + (lane & 31) * 4;
            gll16(gsrc, &wsh[p * WPAIR]);
        }
        // ---- x fragments + scales for this chunk: issue before barrier ----
        float8 xa0 = *(const float8*)(gx0 + c * BK + woff);
        float8 xb0 = *(const float8*)(gx1 + c * BK + woff);
        float8 xa1 = *(const float8*)(gx0 + c * BK + woff + 32);
        float8 xb1 = *(const float8*)(gx1 + c * BK + woff + 32);
        const int grp = (kc >> 7) + (w >> 1); // wave's 64 k sit in one group
        const float sA = scales[(n0 + row) * NGROUPS + grp];
        const float sB = scales[(n0 + 16 + row) * NGROUPS + grp];
        half8 a00 = cvt8(xa0), a10 = cvt8(xb0); // halves live regs across barrier
        half8 a01 = cvt8(xa1), a11 = cvt8(xb1);
        __syncthreads();

        // ---- compute: wave w owns local k [woff, woff+64) = 2 MFMA steps ----
        floatx4 t00 = {0,0,0,0}, t01 = {0,0,0,0};
        floatx4 t10 = {0,0,0,0}, t11 = {0,0,0,0};
        #pragma unroll
        for (int kk = 0; kk < 2; ++kk) {
            const int kl = woff + kk * 32;
            const int bidx = (row >> 1) * WPAIR + (row & 1) * 128 + (kl >> 1) + quad * 4;
            half8 b0 = unpack8(*(const int4*)&wsh[bidx]);               // n0+row
            half8 b1 = unpack8(*(const int4*)&wsh[bidx + 8 * WPAIR]);   // n0+16+row
            half8 a0 = kk ? a01 : a00;
            half8 a1 = kk ? a11 : a10;
            t00 = __builtin_amdgcn_mfma_f32_16x16x32_f16(a0, b0, t00, 0, 0, 0);
            t01 = __builtin_amdgcn_mfma_f32_16x16x32_f16(a0, b1, t01, 0, 0, 0);
            t10 = __builtin_amdgcn_mfma_f32_16x16x32_f16(a1, b0, t10, 0, 0, 0);
            t11 = __builtin_amdgcn_mfma_f32_16x16x32_f16(a1, b1, t11, 0, 0, 0);
        }
        #pragma unroll
        for (int r = 0; r < 4; ++r) {
            acc00[r] += sA * t00[r]; // fp32 scale application, matches reference
            acc01[r] += sB * t01[r];
            acc10[r] += sA * t10[r];
            acc11[r] += sB * t11[r];
        }
        __syncthreads();
    }

    // ---- epilogue: reduce 4 waves' k-partials in LDS, one atomic per out ----
    float* rw = red + w * RWAVE;
    #pragma unroll
    for (int r = 0; r < 4; ++r) {
        // C/D layout: col(n) = lane&15, row(m) = quad*4 + r
        const int m0 = quad * 4 + r;
        rw[m0 * RSTRIDE + row]             = acc00[r];
        rw[m0 * RSTRIDE + 16 + row]        = acc01[r];
        rw[(m0 + 16) * RSTRIDE + row]      = acc10[r];
        rw[(m0 + 16) * RSTRIDE + 16 + row] = acc11[r];
    }
    __syncthreads();
    #pragma unroll
    for (int i = 0; i < 4; ++i) {
        const int o = t + 256 * i;      // o = m*32 + n, 1024 outputs
        const int m = o >> 5;
        const int n = o & 31;
        const int a = m * RSTRIDE + n;
        const float sum = red[a] + red[RWAVE + a] + red[2 * RWAVE + a] + red[3 * RWAVE + a];
        atomicAdd(&out[m * N + n0 + n], sum);
    }
}

extern "C" void kernel_launch(void* const* d_in, const int* in_sizes, int n_in,
                              void* d_out, int out_size, void* d_ws, size_t ws_size,
                              hipStream_t stream) {
    const float* x      = (const float*)d_in[0];
    const int* wp       = (const int*)d_in[1];
    const float* scales = (const float*)d_in[2];
    float* out          = (float*)d_out;

    (void)hipMemsetAsync(out, 0, (size_t)M * N * sizeof(float), stream);
    int4_gemm_kernel<<<dim3(N / BN, KSPLIT), 256, 0, stream>>>(x, wp, scales, out);
}